// Round 11
// baseline (144.362 us; speedup 1.0000x reference)
//
#include <hip/hip_runtime.h>

typedef unsigned short u16;
typedef unsigned int u32;
typedef __attribute__((ext_vector_type(8))) short short8;
typedef __attribute__((ext_vector_type(4))) float f32x4;

__device__ __forceinline__ u16 f2b(float f) {
  union { float f; u32 i; } v; v.f = f;
  u32 i = v.i;
  return (u16)((i + 0x7FFFu + ((i >> 16) & 1u)) >> 16);
}
__device__ __forceinline__ float lo16(u32 x) { union { u32 i; float f; } v; v.i = x << 16; return v.f; }
__device__ __forceinline__ float hi16(u32 x) { union { u32 i; float f; } v; v.i = x & 0xffff0000u; return v.f; }
__device__ __forceinline__ u32 pack2(float a, float b) { return (u32)f2b(a) | ((u32)f2b(b) << 16); }

// Sizes: N=2, M=512, D_IN=64, D=128, H=8. Rows = N*M = 1024. hn = h*2+n in [0,16).
__device__ __align__(16) float g_h[1024 * 128];
__device__ __align__(16) u16   g_hb[1024 * 128];
__device__ __align__(16) u16   g_Wt[24 * 128 * 128];   // W^T per (proj,head): [ph][e][d] bf16
__device__ __align__(16) u16   g_w1t[128 * 1024];      // fv_w1^T: [e][k] bf16
__device__ __align__(16) u16   g_K[16 * 512 * 128];
__device__ __align__(16) u16   g_Q[16 * 512 * 128];
__device__ __align__(16) u16   g_V[16 * 512 * 128];
__device__ __align__(16) u16   g_Opb[512 * 64 * 128];  // bf16 flash partials
__device__ __align__(16) float g_ml[512 * 64 * 2];
__device__ __align__(16) float g_part8[8 * 1024 * 128];
__device__ __align__(16) float g_A[1024 * 128];
__device__ __align__(16) float g_Bm[1024 * 128];

// ---------------- Kernel 1: f_node (+ coalesced LDS-tile weight transpose) -------
// Each of the 512 blocks also transposes one 32x32 tile:
//   tiles 0..383: wk/wq/wv -> g_Wt ; tiles 384..511: fv_w1 -> g_w1t.
__global__ void k_fnode(const float* __restrict__ x, const float* __restrict__ w1,
                        const float* __restrict__ b1, const float* __restrict__ w2,
                        const float* __restrict__ b2, const float* __restrict__ wk,
                        const float* __restrict__ wq, const float* __restrict__ wv,
                        const float* __restrict__ fvw1) {
  __shared__ float xr[2 * 64];
  __shared__ float hids[2 * 256];
  __shared__ float red[2048];
  __shared__ float tile[32 * 33];
  int tx = threadIdx.x;
  int row0 = blockIdx.x * 2;
  if (tx < 128) {
    int r = tx >> 6, k = tx & 63;
    xr[tx] = x[(row0 + r) * 64 + k] + sinf((float)k * (5.0f / 63.0f));
  }
  // ---- piggyback transpose: one 32x32 tile per block, LDS-coalesced ----
  {
    int t = blockIdx.x;
    const float* src; u16* dst;
    int src_row0, src_col0, src_ld, dst_row0, dst_col0, dst_ld;
    if (t < 384) {
      int ph = t >> 4, rem = t & 15;        // ph = proj*8+head
      int proj = ph >> 3, head = ph & 7;
      int tr = rem >> 2, tc = rem & 3;      // out tile (e-dim, d-dim)
      const float* W = (proj == 0) ? wk : (proj == 1) ? wq : wv;
      src = W + head * 16384;               // [d][e] 128x128
      src_row0 = tc * 32; src_col0 = tr * 32; src_ld = 128;  // rows=d, cols=e
      dst = g_Wt + ph * 16384;              // [e][d] 128x128
      dst_row0 = tr * 32; dst_col0 = tc * 32; dst_ld = 128;
    } else {
      int t2 = t - 384;
      int et = t2 >> 5, kt = t2 & 31;       // out [e][k] 128x1024
      src = fvw1;                           // [k][e] 1024x128
      src_row0 = kt * 32; src_col0 = et * 32; src_ld = 128;
      dst = g_w1t;
      dst_row0 = et * 32; dst_col0 = kt * 32; dst_ld = 1024;
    }
    int r = tx >> 3, c4 = (tx & 7) * 4;
    float4 v = *(const float4*)&src[(src_row0 + r) * src_ld + src_col0 + c4];
    tile[(c4 + 0) * 33 + r] = v.x;
    tile[(c4 + 1) * 33 + r] = v.y;
    tile[(c4 + 2) * 33 + r] = v.z;
    tile[(c4 + 3) * 33 + r] = v.w;
    __syncthreads();
    float t0 = tile[r * 33 + c4 + 0], t1 = tile[r * 33 + c4 + 1];
    float t2v = tile[r * 33 + c4 + 2], t3 = tile[r * 33 + c4 + 3];
    *(uint2*)&dst[(dst_row0 + r) * dst_ld + dst_col0 + c4] =
        make_uint2(pack2(t0, t1), pack2(t2v, t3));
  }
  __syncthreads();
  {
    int ks = tx >> 6, cg = tx & 63;
    float acc[2][4] = {};
#pragma unroll 4
    for (int i = 0; i < 16; i++) {
      int k = ks * 16 + i;
      float4 w4 = *(const float4*)&w1[k * 256 + cg * 4];
      float a0 = xr[k], a1 = xr[64 + k];
      acc[0][0] = fmaf(a0, w4.x, acc[0][0]); acc[0][1] = fmaf(a0, w4.y, acc[0][1]);
      acc[0][2] = fmaf(a0, w4.z, acc[0][2]); acc[0][3] = fmaf(a0, w4.w, acc[0][3]);
      acc[1][0] = fmaf(a1, w4.x, acc[1][0]); acc[1][1] = fmaf(a1, w4.y, acc[1][1]);
      acc[1][2] = fmaf(a1, w4.z, acc[1][2]); acc[1][3] = fmaf(a1, w4.w, acc[1][3]);
    }
#pragma unroll
    for (int r = 0; r < 2; r++)
      *(float4*)&red[ks * 512 + r * 256 + cg * 4] = *(float4*)acc[r];
  }
  __syncthreads();
#pragma unroll
  for (int jo = 0; jo < 2; jo++) {
    int o = jo * 256 + tx;
    float s = red[o] + red[512 + o] + red[1024 + o] + red[1536 + o];
    hids[o] = fmaxf(s + b1[o & 255], 0.0f);
  }
  __syncthreads();
  {
    int ks = tx >> 5, eg = tx & 31;
    float acc[2][4] = {};
#pragma unroll 4
    for (int i = 0; i < 32; i++) {
      int k = ks * 32 + i;
      float4 w4 = *(const float4*)&w2[k * 128 + eg * 4];
      float a0 = hids[k], a1 = hids[256 + k];
      acc[0][0] = fmaf(a0, w4.x, acc[0][0]); acc[0][1] = fmaf(a0, w4.y, acc[0][1]);
      acc[0][2] = fmaf(a0, w4.z, acc[0][2]); acc[0][3] = fmaf(a0, w4.w, acc[0][3]);
      acc[1][0] = fmaf(a1, w4.x, acc[1][0]); acc[1][1] = fmaf(a1, w4.y, acc[1][1]);
      acc[1][2] = fmaf(a1, w4.z, acc[1][2]); acc[1][3] = fmaf(a1, w4.w, acc[1][3]);
    }
    __syncthreads();
#pragma unroll
    for (int r = 0; r < 2; r++)
      *(float4*)&red[ks * 256 + r * 128 + eg * 4] = *(float4*)acc[r];
  }
  __syncthreads();
  {
    float s = 0.0f;
#pragma unroll
    for (int ks = 0; ks < 8; ks++) s += red[ks * 256 + tx];
    int r = tx >> 7, e = tx & 127;
    float v = s + b2[e];
    g_h[(row0 + r) * 128 + e] = v;
    g_hb[(row0 + r) * 128 + e] = f2b(v);
  }
}

// ---------------- Kernel 2: K/Q/V projections via MFMA (pre-transposed W) --------
__global__ __launch_bounds__(256) void k_kqv(
    const float* __restrict__ bk, const float* __restrict__ bq,
    const float* __restrict__ bv) {
  __shared__ u16 hs[64 * 136];
  __shared__ u16 Wt[128 * 136];
  int b = blockIdx.x, tx = threadIdx.x;
  int rt = b & 15, ph = b >> 4;
  int proj = ph >> 3, head = ph & 7;
  const float* Bb = (proj == 0) ? bk : (proj == 1) ? bq : bv;
  u16* O = (proj == 0) ? g_K : (proj == 1) ? g_Q : g_V;
  int r0 = rt * 64;
#pragma unroll
  for (int t = 0; t < 4; t++) {
    int idx = t * 256 + tx, row = idx >> 4, oct = idx & 15;
    *(uint4*)&hs[row * 136 + oct * 8] = *(const uint4*)&g_hb[(r0 + row) * 128 + oct * 8];
  }
  const u16* Wtg = g_Wt + ph * 16384;
#pragma unroll
  for (int t = 0; t < 8; t++) {
    int idx = t * 256 + tx, row = idx >> 4, oct = idx & 15;
    *(uint4*)&Wt[row * 136 + oct * 8] = *(const uint4*)&Wtg[row * 128 + oct * 8];
  }
  __syncthreads();
  int lane = tx & 63, wv_ = tx >> 6, cl = lane & 15, quad = lane >> 4;
  short8 bH[4];
#pragma unroll
  for (int kk = 0; kk < 4; kk++)
    bH[kk] = *(const short8*)&hs[(wv_ * 16 + cl) * 136 + kk * 32 + quad * 8];
  f32x4 zero = {0.0f, 0.0f, 0.0f, 0.0f};
  f32x4 acc[8];
#pragma unroll
  for (int em = 0; em < 8; em++) acc[em] = zero;
#pragma unroll
  for (int em = 0; em < 8; em++)
#pragma unroll
    for (int kk = 0; kk < 4; kk++) {
      short8 aW = *(const short8*)&Wt[(em * 16 + cl) * 136 + kk * 32 + quad * 8];
      acc[em] = __builtin_amdgcn_mfma_f32_16x16x32_bf16(aW, bH[kk], acc[em], 0, 0, 0);
    }
#pragma unroll
  for (int em = 0; em < 8; em++) {
    float4 b4 = *(const float4*)&Bb[head * 128 + em * 16 + quad * 4];
    uint2 st = make_uint2(pack2(acc[em][0] + b4.x, acc[em][1] + b4.y),
                          pack2(acc[em][2] + b4.z, acc[em][3] + b4.w));
    *(uint2*)&O[(head * 1024 + r0 + wv_ * 16 + cl) * 128 + em * 16 + quad * 4] = st;
  }
}

// ---------------- Kernel 3: attention via MFMA, bf16 partials out ----------------
__global__ __launch_bounds__(256) void k_attn() {
  __shared__ u16 Ks[64 * 136];
  __shared__ u16 Qs[64 * 136];
  __shared__ u16 Vt[128 * 72];
  __shared__ u16 Pw[4 * 16 * 72];
  __shared__ float alphas[4 * 16];
  int b = blockIdx.x, tx = threadIdx.x;
  int jc = b & 3, it = (b >> 2) & 7, hn = b >> 5;
  int i0 = it * 64;
  const u16* Kp = g_K + hn * 65536;
  const u16* Qp = g_Q + hn * 65536;
  const u16* Vp = g_V + hn * 65536;
#pragma unroll
  for (int t = 0; t < 4; t++) {
    int idx = t * 256 + tx, row = idx >> 4, oct = idx & 15;
    *(uint4*)&Ks[row * 136 + oct * 8] = *(const uint4*)&Kp[(i0 + row) * 128 + oct * 8];
  }
  int lane = tx & 63, wv = tx >> 6;
  int cl = lane & 15, quad = lane >> 4;
  f32x4 zero = {0.0f, 0.0f, 0.0f, 0.0f};
  f32x4 o[8];
#pragma unroll
  for (int es = 0; es < 8; es++) o[es] = zero;
  float m_ = -1e30f, l_ = 0.0f;

  for (int jt = 0; jt < 2; jt++) {
    int j0 = jc * 128 + jt * 64;
    __syncthreads();
#pragma unroll
    for (int t = 0; t < 4; t++) {
      int idx = t * 256 + tx, row = idx >> 4, oct = idx & 15;
      *(uint4*)&Qs[row * 136 + oct * 8] = *(const uint4*)&Qp[(j0 + row) * 128 + oct * 8];
    }
    {
      int jg = (tx & 15) * 4, e8 = (tx >> 4) * 8;
      uint4 r0 = *(const uint4*)&Vp[(j0 + jg + 0) * 128 + e8];
      uint4 r1 = *(const uint4*)&Vp[(j0 + jg + 1) * 128 + e8];
      uint4 r2 = *(const uint4*)&Vp[(j0 + jg + 2) * 128 + e8];
      uint4 r3 = *(const uint4*)&Vp[(j0 + jg + 3) * 128 + e8];
      const u32* p0 = (const u32*)&r0; const u32* p1 = (const u32*)&r1;
      const u32* p2 = (const u32*)&r2; const u32* p3 = (const u32*)&r3;
#pragma unroll
      for (int c = 0; c < 8; c++) {
        int w = c >> 1, sh = (c & 1) * 16;
        u32 lo = ((p0[w] >> sh) & 0xffffu) | (((p1[w] >> sh) & 0xffffu) << 16);
        u32 hi = ((p2[w] >> sh) & 0xffffu) | (((p3[w] >> sh) & 0xffffu) << 16);
        *(uint2*)&Vt[(e8 + c) * 72 + jg] = make_uint2(lo, hi);
      }
    }
    __syncthreads();
    short8 bK[4];
#pragma unroll
    for (int kk = 0; kk < 4; kk++)
      bK[kk] = *(const short8*)&Ks[(wv * 16 + cl) * 136 + kk * 32 + quad * 8];
    f32x4 st[4];
#pragma unroll
    for (int s = 0; s < 4; s++) {
      f32x4 acc = zero;
#pragma unroll
      for (int kk = 0; kk < 4; kk++) {
        short8 aQ = *(const short8*)&Qs[(s * 16 + cl) * 136 + kk * 32 + quad * 8];
        acc = __builtin_amdgcn_mfma_f32_16x16x32_bf16(aQ, bK[kk], acc, 0, 0, 0);
      }
      st[s] = acc;
    }
    float p[4][4];
    float tm = -1e30f;
#pragma unroll
    for (int s = 0; s < 4; s++)
#pragma unroll
      for (int r = 0; r < 4; r++) {
        float v = st[s][r];
        v = fmaxf(v, 0.2f * v);
        p[s][r] = v;
        tm = fmaxf(tm, v);
      }
    tm = fmaxf(tm, __shfl_xor(tm, 16));
    tm = fmaxf(tm, __shfl_xor(tm, 32));
    float mn = fmaxf(m_, tm);
    float alpha = __expf(m_ - mn);
    m_ = mn;
    float ps = 0.0f;
#pragma unroll
    for (int s = 0; s < 4; s++)
#pragma unroll
      for (int r = 0; r < 4; r++) {
        float e = __expf(p[s][r] - mn);
        p[s][r] = e;
        ps += e;
      }
    ps += __shfl_xor(ps, 16);
    ps += __shfl_xor(ps, 32);
    l_ = l_ * alpha + ps;
#pragma unroll
    for (int s = 0; s < 4; s++) {
      uint2 w2v = make_uint2(pack2(p[s][0], p[s][1]), pack2(p[s][2], p[s][3]));
      *(uint2*)&Pw[(wv * 16 + cl) * 72 + s * 16 + quad * 4] = w2v;
    }
    if (quad == 0) alphas[wv * 16 + cl] = alpha;
    __syncthreads();
    f32x4 av = *(const f32x4*)&alphas[wv * 16 + quad * 4];
#pragma unroll
    for (int es = 0; es < 8; es++) o[es] *= av;
    short8 aP[2];
#pragma unroll
    for (int k2 = 0; k2 < 2; k2++)
      aP[k2] = *(const short8*)&Pw[(wv * 16 + cl) * 72 + k2 * 32 + quad * 8];
#pragma unroll
    for (int es = 0; es < 8; es++) {
#pragma unroll
      for (int k2 = 0; k2 < 2; k2++) {
        short8 bV = *(const short8*)&Vt[(es * 16 + cl) * 72 + k2 * 32 + quad * 8];
        o[es] = __builtin_amdgcn_mfma_f32_16x16x32_bf16(aP[k2], bV, o[es], 0, 0, 0);
      }
    }
  }
#pragma unroll
  for (int es = 0; es < 8; es++)
#pragma unroll
    for (int r = 0; r < 4; r++)
      g_Opb[(b * 64 + wv * 16 + quad * 4 + r) * 128 + es * 16 + cl] = f2b(o[es][r]);
  if (quad == 0) {
    g_ml[(b * 64 + wv * 16 + cl) * 2 + 0] = m_;
    g_ml[(b * 64 + wv * 16 + cl) * 2 + 1] = l_;
  }
}

// ---------------- Kernel 4a: fused merge + att@fv_w1 via MFMA --------------------
__global__ __launch_bounds__(256) void k_fv1() {
  __shared__ u16 atts[64 * 136];
  __shared__ u16 w1t[128 * 136];
  int b = blockIdx.x, tx = threadIdx.x;
  int kc = b & 7, rt = b >> 3;
  int r0 = rt * 64, k0 = kc * 128;
  int hn = kc * 2 + (rt >> 3), it = rt & 7;
#pragma unroll
  for (int t = 0; t < 8; t++) {
    int idx = t * 256 + tx, row = idx >> 4, oct = idx & 15;
    *(uint4*)&w1t[row * 136 + oct * 8] = *(const uint4*)&g_w1t[row * 1024 + k0 + oct * 8];
  }
  {
    int row = tx >> 2, cs = (tx & 3) * 32;
    float mc[4], lc[4];
#pragma unroll
    for (int c = 0; c < 4; c++) {
      float2 ml = *(const float2*)&g_ml[((hn * 32 + it * 4 + c) * 64 + row) * 2];
      mc[c] = ml.x; lc[c] = ml.y;
    }
    float ms = fmaxf(fmaxf(mc[0], mc[1]), fmaxf(mc[2], mc[3]));
    float lsum = 0.0f;
    float ra[32];
#pragma unroll
    for (int i = 0; i < 32; i++) ra[i] = 0.0f;
#pragma unroll
    for (int c = 0; c < 4; c++) {
      float w = __expf(mc[c] - ms);
      lsum += w * lc[c];
      const u16* src = &g_Opb[((hn * 32 + it * 4 + c) * 64 + row) * 128 + cs];
#pragma unroll
      for (int ov = 0; ov < 4; ov++) {
        uint4 v = *(const uint4*)&src[ov * 8];
        ra[ov * 8 + 0] = fmaf(w, lo16(v.x), ra[ov * 8 + 0]);
        ra[ov * 8 + 1] = fmaf(w, hi16(v.x), ra[ov * 8 + 1]);
        ra[ov * 8 + 2] = fmaf(w, lo16(v.y), ra[ov * 8 + 2]);
        ra[ov * 8 + 3] = fmaf(w, hi16(v.y), ra[ov * 8 + 3]);
        ra[ov * 8 + 4] = fmaf(w, lo16(v.z), ra[ov * 8 + 4]);
        ra[ov * 8 + 5] = fmaf(w, hi16(v.z), ra[ov * 8 + 5]);
        ra[ov * 8 + 6] = fmaf(w, lo16(v.w), ra[ov * 8 + 6]);
        ra[ov * 8 + 7] = fmaf(w, hi16(v.w), ra[ov * 8 + 7]);
      }
    }
    float inv = 1.0f / lsum;
    u32 pk[16];
#pragma unroll
    for (int i = 0; i < 16; i++) {
      float v0 = ra[i * 2] * inv;     v0 = fmaxf(v0, 0.2f * v0);
      float v1 = ra[i * 2 + 1] * inv; v1 = fmaxf(v1, 0.2f * v1);
      pk[i] = pack2(v0, v1);
    }
#pragma unroll
    for (int ov = 0; ov < 4; ov++)
      *(uint4*)&atts[row * 136 + cs + ov * 8] =
          make_uint4(pk[ov * 4], pk[ov * 4 + 1], pk[ov * 4 + 2], pk[ov * 4 + 3]);
  }
  __syncthreads();
  int lane = tx & 63, wv_ = tx >> 6, cl = lane & 15, quad = lane >> 4;
  short8 bA[4];
#pragma unroll
  for (int kk = 0; kk < 4; kk++)
    bA[kk] = *(const short8*)&atts[(wv_ * 16 + cl) * 136 + kk * 32 + quad * 8];
  f32x4 zero = {0.0f, 0.0f, 0.0f, 0.0f};
  f32x4 acc[8];
#pragma unroll
  for (int em = 0; em < 8; em++) acc[em] = zero;
#pragma unroll
  for (int em = 0; em < 8; em++)
#pragma unroll
    for (int kk = 0; kk < 4; kk++) {
      short8 aW = *(const short8*)&w1t[(em * 16 + cl) * 136 + kk * 32 + quad * 8];
      acc[em] = __builtin_amdgcn_mfma_f32_16x16x32_bf16(aW, bA[kk], acc[em], 0, 0, 0);
    }
#pragma unroll
  for (int em = 0; em < 8; em++)
    *(f32x4*)&g_part8[kc * 131072 + (r0 + wv_ * 16 + cl) * 128 + em * 16 + quad * 4] =
        acc[em];
}

// ---------------- Kernel 4b: bias+relu, @fv_w2, residual, A/B projections --------
__global__ void k_fv2(const float* __restrict__ b1, const float* __restrict__ w2,
                      const float* __restrict__ b2, const float* __restrict__ few1,
                      const float* __restrict__ feb1, float* __restrict__ x2out) {
  __shared__ float hids[2 * 128];
  __shared__ float x2s[2 * 128];
  __shared__ float red[8 * 256];
  int b = blockIdx.x, tx = threadIdx.x;
  int row0 = b * 2;
  {
    int r = tx >> 7, e = tx & 127;
    int gi = (row0 + r) * 128 + e;
    float s = b1[e];
#pragma unroll
    for (int kc = 0; kc < 8; kc++) s += g_part8[kc * 131072 + gi];
    hids[tx] = fmaxf(s, 0.0f);
  }
  __syncthreads();
  int ks = tx >> 5, eg = tx & 31;
  {
    float acc[2][4] = {};
#pragma unroll 4
    for (int i = 0; i < 16; i++) {
      int k = ks * 16 + i;
      float4 w4 = *(const float4*)&w2[k * 128 + eg * 4];
      float a0 = hids[k], a1 = hids[128 + k];
      acc[0][0] = fmaf(a0, w4.x, acc[0][0]); acc[0][1] = fmaf(a0, w4.y, acc[0][1]);
      acc[0][2] = fmaf(a0, w4.z, acc[0][2]); acc[0][3] = fmaf(a0, w4.w, acc[0][3]);
      acc[1][0] = fmaf(a1, w4.x, acc[1][0]); acc[1][1] = fmaf(a1, w4.y, acc[1][1]);
      acc[1][2] = fmaf(a1, w4.z, acc[1][2]); acc[1][3] = fmaf(a1, w4.w, acc[1][3]);
    }
#pragma unroll
    for (int r = 0; r < 2; r++)
      *(float4*)&red[ks * 256 + r * 128 + eg * 4] = *(float4*)acc[r];
  }
  __syncthreads();
  {
    float s = 0.0f;
#pragma unroll
    for (int k8 = 0; k8 < 8; k8++) s += red[k8 * 256 + tx];
    int r = tx >> 7, e = tx & 127;
    int gi = (row0 + r) * 128 + e;
    float c = s + b2[e] + g_h[gi];
    x2s[tx] = c;
    x2out[gi] = c;
  }
  __syncthreads();
  float aA[2][4] = {}, aB[2][4] = {};
#pragma unroll 4
  for (int i = 0; i < 16; i++) {
    int k = ks * 16 + i;
    float4 wa = *(const float4*)&few1[k * 128 + eg * 4];
    float4 wb = *(const float4*)&few1[(128 + k) * 128 + eg * 4];
    float a0 = x2s[k], a1 = x2s[128 + k];
    aA[0][0] = fmaf(a0, wa.x, aA[0][0]); aA[0][1] = fmaf(a0, wa.y, aA[0][1]);
    aA[0][2] = fmaf(a0, wa.z, aA[0][2]); aA[0][3] = fmaf(a0, wa.w, aA[0][3]);
    aA[1][0] = fmaf(a1, wa.x, aA[1][0]); aA[1][1] = fmaf(a1, wa.y, aA[1][1]);
    aA[1][2] = fmaf(a1, wa.z, aA[1][2]); aA[1][3] = fmaf(a1, wa.w, aA[1][3]);
    aB[0][0] = fmaf(a0, wb.x, aB[0][0]); aB[0][1] = fmaf(a0, wb.y, aB[0][1]);
    aB[0][2] = fmaf(a0, wb.z, aB[0][2]); aB[0][3] = fmaf(a0, wb.w, aB[0][3]);
    aB[1][0] = fmaf(a1, wb.x, aB[1][0]); aB[1][1] = fmaf(a1, wb.y, aB[1][1]);
    aB[1][2] = fmaf(a1, wb.z, aB[1][2]); aB[1][3] = fmaf(a1, wb.w, aB[1][3]);
  }
  __syncthreads();
#pragma unroll
  for (int r = 0; r < 2; r++)
    *(float4*)&red[ks * 256 + r * 128 + eg * 4] = *(float4*)aA[r];
  __syncthreads();
  {
    float s = 0.0f;
#pragma unroll
    for (int k8 = 0; k8 < 8; k8++) s += red[k8 * 256 + tx];
    int r = tx >> 7, e = tx & 127;
    g_A[(row0 + r) * 128 + e] = s + feb1[e];
  }
  __syncthreads();
#pragma unroll
  for (int r = 0; r < 2; r++)
    *(float4*)&red[ks * 256 + r * 128 + eg * 4] = *(float4*)aB[r];
  __syncthreads();
  {
    float s = 0.0f;
#pragma unroll
    for (int k8 = 0; k8 < 8; k8++) s += red[k8 * 256 + tx];
    int r = tx >> 7, e = tx & 127;
    g_Bm[(row0 + r) * 128 + e] = s;
  }
}

// ---------------- Kernel 5: pairwise edge FFN (A_i + B_j factorized) -------------
__global__ void k_edge(const float* __restrict__ few2, const float* __restrict__ feb2,
                       float* __restrict__ edge) {
  __shared__ float As[4 * 128];
  __shared__ float w2s[128];
  int b = blockIdx.x, tx = threadIdx.x;
  int n = b >> 8, rest = b & 255, ig = rest >> 1, jh = rest & 1;
  int i0 = ig * 4;
  if (tx < 128) w2s[tx] = few2[tx];
  As[tx] = g_A[(n * 512 + i0) * 128 + tx];
  As[tx + 256] = g_A[(n * 512 + i0) * 128 + tx + 256];
  float eb2 = feb2[0];
  __syncthreads();
  int j = jh * 256 + tx;
  const float* B0 = &g_Bm[(n * 512 + j) * 128];
  float acc[4] = {};
#pragma unroll 4
  for (int dc = 0; dc < 32; dc++) {
    float4 bv = *(const float4*)&B0[dc * 4];
    float4 w4 = *(const float4*)&w2s[dc * 4];
#pragma unroll
    for (int i = 0; i < 4; i++) {
      float4 a4 = *(const float4*)&As[i * 128 + dc * 4];
      acc[i] = fmaf(fmaxf(a4.x + bv.x, 0.0f), w4.x, acc[i]);
      acc[i] = fmaf(fmaxf(a4.y + bv.y, 0.0f), w4.y, acc[i]);
      acc[i] = fmaf(fmaxf(a4.z + bv.z, 0.0f), w4.z, acc[i]);
      acc[i] = fmaf(fmaxf(a4.w + bv.w, 0.0f), w4.w, acc[i]);
    }
  }
  const float scale = 1.0f / 512.0f;
#pragma unroll
  for (int i = 0; i < 4; i++)
    edge[(n * 512 + i0 + i) * 512 + j] = (acc[i] + eb2) * scale;
}

extern "C" void kernel_launch(void* const* d_in, const int* in_sizes, int n_in,
                              void* d_out, int out_size, void* d_ws, size_t ws_size,
                              hipStream_t stream) {
  (void)in_sizes; (void)n_in; (void)out_size; (void)d_ws; (void)ws_size;
  const float* x     = (const float*)d_in[0];
  const float* fn_w1 = (const float*)d_in[1];
  const float* fn_b1 = (const float*)d_in[2];
  const float* fn_w2 = (const float*)d_in[3];
  const float* fn_b2 = (const float*)d_in[4];
  const float* wk    = (const float*)d_in[5];
  const float* bk    = (const float*)d_in[6];
  const float* wq    = (const float*)d_in[7];
  const float* bq    = (const float*)d_in[8];
  const float* wv    = (const float*)d_in[9];
  const float* bv    = (const float*)d_in[10];
  const float* fv_w1 = (const float*)d_in[11];
  const float* fv_b1 = (const float*)d_in[12];
  const float* fv_w2 = (const float*)d_in[13];
  const float* fv_b2 = (const float*)d_in[14];
  const float* fe_w1 = (const float*)d_in[15];
  const float* fe_b1 = (const float*)d_in[16];
  const float* fe_w2 = (const float*)d_in[17];
  const float* fe_b2 = (const float*)d_in[18];

  float* x2out = (float*)d_out;      // [0, 131072) floats
  float* edge  = x2out + 131072;     // [131072, 655360) floats

  k_fnode<<<512, 256, 0, stream>>>(x, fn_w1, fn_b1, fn_w2, fn_b2, wk, wq, wv, fv_w1);
  k_kqv<<<384, 256, 0, stream>>>(bk, bq, bv);
  k_attn<<<512, 256, 0, stream>>>();
  k_fv1<<<128, 256, 0, stream>>>();
  k_fv2<<<512, 256, 0, stream>>>(fv_b1, fv_w2, fv_b2, fe_w1, fe_b1, x2out);
  k_edge<<<512, 256, 0, stream>>>(fe_w2, fe_b2, edge);
}